// Round 9
// baseline (310.397 us; speedup 1.0000x reference)
//
#include <hip/hip_runtime.h>
#include <hip/hip_bf16.h>

typedef __attribute__((ext_vector_type(8))) short short8;   // 8 bf16 = 4 VGPRs
typedef __attribute__((ext_vector_type(4))) float f32x4;

constexpr int C  = 16;
constexpr int DD = 128, HH = 128, WW = 16;
constexpr int HW = HH * WW;        // 2048
constexpr int SP = DD * HW;        // 262144
constexpr int TOT = C * SP;        // 4194304

// Padded bf16 activation layout: [dp=134][hp=134][wp=20][ci=16]
constexpr int WP_ = 20, HP_ = 134, DP_ = 134;
constexpr int ROWE   = WP_ * C;        // 320 elems (640 B) per row
constexpr int PLANEE = HP_ * ROWE;     // 42880
constexpr int PADE   = DP_ * PLANEE;   // 5,745,920 elems

using gas_ptr = const __attribute__((address_space(1))) void*;
using las_ptr = __attribute__((address_space(3))) void*;

// ---------------------------------------------------------------------------
// Single-plane-phase MFMA conv + fused BN (5x5x3 / 7x7x5).
// Block 256 = 4 waves = 2 h-windows (pid) x 2 K-split members (m).
// K-split by (kh*KWP+kwp) parity: BOTH members consume the SAME staged
// dz-plane (kd = u), so each phase stages ONE 14 KB plane, double-buffered
// -> 32 KB LDS -> 4 blocks/CU, 16 waves/CU (4/SIMD), 4 independent blocks.
// Grid = 128 d x 8 hb = 1024 blocks, XCD-chunk swizzled.
// ---------------------------------------------------------------------------
template <int KD, int KH, int KW, bool ACCUM, bool BN>
__global__ __launch_bounds__(256, 4)
void conv_plane(const short* __restrict__ xp, const short* __restrict__ wpk,
                const float* __restrict__ bn_g, const float* __restrict__ bn_b,
                const float* __restrict__ bn_m, const float* __restrict__ bn_v,
                int layer, float* __restrict__ F)
{
    constexpr int PD = (KD - 1) / 2, PH = (KH - 1) / 2, PW = (KW - 1) / 2;
    constexpr int KWP = (KW + 1) / 2;
    constexpr int NB  = 8 + KH - 1;        // B halo rows per wave window
    constexpr int NR  = 16 + KH - 1;       // staged rows per plane (both pids)
    constexpr int NCHP = NR * 40;          // 16B chunks per plane
    constexpr int STIT = (NCHP + 255) / 256;
    static_assert(STIT == 4, "vmcnt literal assumes 4 stage loads");
    constexpr int BUFSZ = STIT * 256 * 16; // 16384 B
    static_assert(2 * BUFSZ >= 2 * 8 * 64 * 16, "merge overlay fits");

    __shared__ alignas(16) char smem[2 * BUFSZ];   // 32768 B

    // XCD-chunk swizzle (1024 % 8 == 0 -> bijective): d-neighbor blocks
    // (which share staged planes) land on the same XCD's L2.
    const int bid  = (blockIdx.x & 7) * 128 + (blockIdx.x >> 3);
    const int d    = bid >> 3, hb = bid & 7;
    const int tid  = threadIdx.x;
    const int wid  = tid >> 6, lane = tid & 63;
    const int pid  = wid >> 1, m = wid & 1;        // h-window, K-split member
    const int l15  = lane & 15;
    const int cih  = (lane >> 4) & 1;
    const int tsel = lane >> 5;

    const char* xb = (const char*)xp;
    const char* wb = (const char*)wpk;
    const int hp0  = hb * 16 + (3 - PH);           // first staged padded-h row

    // Stage plane u (padded dp = d + u + (3-PD)): exactly STIT=4
    // global_load_lds per thread (tail clamped -> deterministic vmcnt).
    auto stage = [&](int buf, int u) {
#pragma unroll
        for (int it = 0; it < STIT; ++it) {
            int chunk = it * 256 + tid;
            int cc = chunk < NCHP ? chunk : NCHP - 1;
            const char* g = xb
                + (size_t)((d + u + (3 - PD)) * PLANEE + hp0 * ROWE) * 2
                + (size_t)cc * 16;
            void* l = (void*)(smem + buf * BUFSZ + (it * 256 + wid * 64) * 16);
            __builtin_amdgcn_global_load_lds((gas_ptr)g, (las_ptr)l, 16, 0, 0);
        }
    };

    f32x4 acc[8] = {};

    stage(0, 0);
#pragma unroll 1
    for (int u = 0; u < KD; ++u) {          // kd = u (TD=1)
        const int cur = u & 1;
        if (u + 1 < KD) {
            stage(cur ^ 1, u + 1);
            asm volatile("s_waitcnt vmcnt(4)" ::: "memory");
        } else {
            asm volatile("s_waitcnt vmcnt(0)" ::: "memory");
        }
        __builtin_amdgcn_s_barrier();        // buf[cur] valid

        const char* lb = smem + cur * BUFSZ + pid * 8 * 640;
#pragma unroll
        for (int kwp = 0; kwp < KWP; ++kwp) {
            if ((KWP & 1) == 0) {            // even KWP: kwp-parity split
                if ((kwp & 1) != m) continue;
            }
            const int kwa = 2 * kwp;
            const int kwb_ = (2 * kwp + 1 < KW) ? 2 * kwp + 1 : KW - 1;
            const unsigned laneoff =
                (unsigned)((l15 + (tsel ? kwb_ : kwa) + (2 - PW)) * 32 + cih * 16);
            short8 Bf[NB];
#pragma unroll
            for (int rB = 0; rB < NB; ++rB)
                Bf[rB] = *(const short8*)(lb + rB * 640 + laneoff);
#pragma unroll
            for (int kh = 0; kh < KH; ++kh) {
                if (KWP & 1) {               // odd KWP: (kh+kwp)-parity split
                    if (((kh + kwp) & 1) != m) continue;
                }
                const short8 a = *(const short8*)(
                    wb + (unsigned)(((u * KH + kh) * KWP + kwp) * 1024 + lane * 16));
#pragma unroll
                for (int r = 0; r < 8; ++r)
                    acc[r] = __builtin_amdgcn_mfma_f32_16x16x32_bf16(
                        a, Bf[r + kh], acc[r], 0, 0, 0);
            }
        }
        __builtin_amdgcn_s_barrier();        // all reads of buf[cur] done
    }

    // K-split merge via LDS overlay (staging drained; reads done).
    float* mlds = (float*)smem;
    if (m == 1) {
#pragma unroll
        for (int r = 0; r < 8; ++r)
            *(f32x4*)&mlds[((pid * 8 + r) * 64 + lane) * 4] = acc[r];
    }
    __syncthreads();
    if (m == 1) return;
#pragma unroll
    for (int r = 0; r < 8; ++r) {
        const f32x4 o = *(const f32x4*)&mlds[((pid * 8 + r) * 64 + lane) * 4];
#pragma unroll
        for (int j = 0; j < 4; ++j) acc[r][j] += o[j];
    }

    float sc[4], sh[4];
    if (BN) {
        const int cb = (lane >> 4) * 4;
        const f32x4 g  = *(const f32x4*)(bn_g + layer * C + cb);
        const f32x4 be = *(const f32x4*)(bn_b + layer * C + cb);
        const f32x4 mm = *(const f32x4*)(bn_m + layer * C + cb);
        const f32x4 v  = *(const f32x4*)(bn_v + layer * C + cb);
#pragma unroll
        for (int j = 0; j < 4; ++j) { sc[j] = g[j] / sqrtf(v[j] + 1e-5f); sh[j] = be[j] - mm[j] * sc[j]; }
    } else {
#pragma unroll
        for (int j = 0; j < 4; ++j) { sc[j] = 1.f; sh[j] = 0.f; }
    }
    const int h0 = hb * 16 + pid * 8;
#pragma unroll
    for (int r = 0; r < 8; ++r) {
        const int h = h0 + r;
        float* dst = F + (unsigned)(((d * HH + h) * WW + l15) * C + (lane >> 4) * 4);
        f32x4 val;
#pragma unroll
        for (int j = 0; j < 4; ++j) val[j] = acc[r][j] * sc[j] + sh[j];
        if (ACCUM) {
            const f32x4 old = *(const f32x4*)dst;
#pragma unroll
            for (int j = 0; j < 4; ++j) val[j] += old[j];
        }
        *(f32x4*)dst = val;
    }
}

// ---------------------------------------------------------------------------
// Small convs (3x3x1 taps=9, 1x1x1 taps=1): round-5 kernel.
// ---------------------------------------------------------------------------
template <int KD, int KH, int KW, int NTAPS, bool ACCUM, bool BN>
__global__ __launch_bounds__(256, 4)
void conv_mfma(const short* __restrict__ xp, const short* __restrict__ wpk,
               const float* __restrict__ bn_g, const float* __restrict__ bn_b,
               const float* __restrict__ bn_m, const float* __restrict__ bn_v,
               int layer, float* __restrict__ F)
{
    constexpr int PD = (KD - 1) / 2, PH = (KH - 1) / 2, PW = (KW - 1) / 2;
    constexpr int NP = (NTAPS + 1) / 2;

    const int b    = blockIdx.x;
    const int d    = b >> 3, hb = b & 7;
    const int tid  = threadIdx.x;
    const int wid  = tid >> 6, lane = tid & 63;
    const int h0   = hb * 16 + wid * 4;

    const int l15  = lane & 15;
    const int cih  = (lane >> 4) & 1;
    const int tsel = lane >> 5;
    const unsigned laneoff = (unsigned)(l15 * 32 + cih * 16);

    unsigned off_r[4];
#pragma unroll
    for (int r = 0; r < 4; ++r) {
        const int h = h0 + r;
        off_r[r] = (unsigned)((((d + (3 - PD)) * HP_ + (h + (3 - PH))) * ROWE
                               + (2 - PW) * C) * 2) + laneoff;
    }

    const char* xb = (const char*)xp;
    const char* wb = (const char*)wpk;

    f32x4 acc[4] = {};
#pragma unroll 2
    for (int p = 0; p < NP; ++p) {
        const int ta = 2 * p;
        const int tb = (2 * p + 1 < NTAPS) ? 2 * p + 1 : NTAPS - 1;
        const int kda = ta / (KH * KW), ra = ta % (KH * KW);
        const int kha = ra / KW,        kwa = ra % KW;
        const int kdb = tb / (KH * KW), rb = tb % (KH * KW);
        const int khb = rb / KW,        kwb = rb % KW;
        const unsigned toa = (unsigned)((kda * PLANEE + kha * ROWE + kwa * C) * 2);
        const unsigned tob = (unsigned)((kdb * PLANEE + khb * ROWE + kwb * C) * 2);
        const unsigned ts  = tsel ? tob : toa;

        const short8 a = *(const short8*)(wb + (unsigned)(p * 1024 + lane * 16));
#pragma unroll
        for (int r = 0; r < 4; ++r) {
            const short8 bf = *(const short8*)(xb + (off_r[r] + ts));
            acc[r] = __builtin_amdgcn_mfma_f32_16x16x32_bf16(a, bf, acc[r], 0, 0, 0);
        }
    }

    float sc[4], sh[4];
    if (BN) {
        const int cb = (lane >> 4) * 4;
        const f32x4 g  = *(const f32x4*)(bn_g + layer * C + cb);
        const f32x4 be = *(const f32x4*)(bn_b + layer * C + cb);
        const f32x4 m  = *(const f32x4*)(bn_m + layer * C + cb);
        const f32x4 v  = *(const f32x4*)(bn_v + layer * C + cb);
#pragma unroll
        for (int j = 0; j < 4; ++j) { sc[j] = g[j] / sqrtf(v[j] + 1e-5f); sh[j] = be[j] - m[j] * sc[j]; }
    } else {
#pragma unroll
        for (int j = 0; j < 4; ++j) { sc[j] = 1.f; sh[j] = 0.f; }
    }
#pragma unroll
    for (int r = 0; r < 4; ++r) {
        const int h = h0 + r;
        float* dst = F + (unsigned)(((d * HH + h) * WW + l15) * C + (lane >> 4) * 4);
        f32x4 val;
#pragma unroll
        for (int j = 0; j < 4; ++j) val[j] = acc[r][j] * sc[j] + sh[j];
        if (ACCUM) {
            const f32x4 old = *(const f32x4*)dst;
#pragma unroll
            for (int j = 0; j < 4; ++j) val[j] += old[j];
        }
        *(f32x4*)dst = val;
    }
}

// ---------------------------------------------------------------------------
__global__ __launch_bounds__(256)
void pack_x(const float* __restrict__ x, short* __restrict__ xp)
{
    const int b  = blockIdx.x;
    const int dp = b / HP_, hp = b % HP_;
    const int t  = threadIdx.x;
    const int d  = dp - 3, h = hp - 3;
    const bool inr = ((unsigned)d < (unsigned)DD) && ((unsigned)h < (unsigned)HH);
    short* row = xp + (unsigned)(dp * PLANEE + hp * ROWE);

    const int w = t & 15, ci = t >> 4;
    float v = 0.f;
    if (inr) v = x[ci * SP + d * HW + h * WW + w];
    __hip_bfloat16 hv = __float2bfloat16(v);
    row[(w + 2) * C + ci] = *(short*)&hv;
    if (t < 64) {
        const int pi = t >> 4;
        const int wp = (pi < 2) ? pi : (16 + pi);
        row[wp * C + (t & 15)] = 0;
    }
}

template <bool RELU, bool ADD>
__global__ __launch_bounds__(256)
void pack_f(float* __restrict__ S, const float* __restrict__ A2,
            short* __restrict__ P)
{
    const int b  = blockIdx.x;
    const int dp = b / HP_, hp = b % HP_;
    const int t  = threadIdx.x;
    const int d  = dp - 3, h = hp - 3;
    const bool inr = ((unsigned)d < (unsigned)DD) && ((unsigned)h < (unsigned)HH);
    short* row = P + (unsigned)(dp * PLANEE + hp * ROWE);

    const int ci = t & 15, w = t >> 4;
    float pv = 0.f;
    if (inr) {
        const unsigned idx = (unsigned)(((d * HH + h) * WW + w) * C + ci);
        const float v = S[idx];
        pv = RELU ? fmaxf(v, 0.f) : v;
        if (ADD) S[idx] = v + A2[idx];
    }
    __hip_bfloat16 hv = __float2bfloat16(pv);
    row[(w + 2) * C + ci] = *(short*)&hv;
    if (t < 64) {
        const int pi = t >> 4;
        const int wp = (pi < 2) ? pi : (16 + pi);
        row[wp * C + (t & 15)] = 0;
    }
}

// ---------------------------------------------------------------------------
// One launch packs all 11 weight tensors.
// ---------------------------------------------------------------------------
struct WSrcs { const float* p[11]; };

__global__ __launch_bounds__(256)
void pack_all(WSrcs ws, short* __restrict__ dst)
{
    constexpr int NW = 11;
    constexpr int style[NW] = {0, 0, 1,  1,   0, 1,  1,   0, 0, 1,  1};
    constexpr int khw[NW]   = {9, 9, 75, 245, 9, 75, 245, 1, 9, 75, 245};
    constexpr int kws[NW]   = {1, 1, 3,  5,   1, 3,  5,   1, 1, 3,  5};
    constexpr int pref[NW + 1] = {0, 5, 10, 60, 207, 212, 262, 409, 410, 415, 465, 612};

    const int b = blockIdx.x;
    int i = 0;
    while (i + 1 < NW + 1 && b >= pref[i + 1]) ++i;
    const int pl = b - pref[i];
    const float* src = ws.p[i];
    const int KHW = khw[i], KW = kws[i], KWP = (KW + 1) / 2;

    const int t  = threadIdx.x;
    const int l  = t >> 2, jj = t & 3;
    const int co = l & 15, cih = (l >> 4) & 1, tp = l >> 5;

    unsigned out = 0;
    if (style[i] == 0) {
        const int tap = 2 * pl + tp;
#pragma unroll
        for (int s = 0; s < 2; ++s) {
            const int ci = cih * 8 + jj * 2 + s;
            const float v = (tap < KHW) ? src[(co * C + ci) * KHW + tap] : 0.f;
            __hip_bfloat16 hv = __float2bfloat16(v);
            out |= ((unsigned)*(unsigned short*)&hv) << (16 * s);
        }
    } else {
        const int row = pl / KWP, kwp = pl % KWP;
        const int kw  = 2 * kwp + tp;
#pragma unroll
        for (int s = 0; s < 2; ++s) {
            const int ci = cih * 8 + jj * 2 + s;
            const float v = (kw < KW) ? src[(co * C + ci) * KHW + row * KW + kw] : 0.f;
            __hip_bfloat16 hv = __float2bfloat16(v);
            out |= ((unsigned)*(unsigned short*)&hv) << (16 * s);
        }
    }
    ((unsigned*)dst)[b * 256 + l * 4 + jj] = out;
}

// ---------------------------------------------------------------------------
__global__ __launch_bounds__(256)
void final_tr(const float* __restrict__ F, float* __restrict__ out)
{
    __shared__ float lds[16 * 17];
    const int b = blockIdx.x;
    const int d = b >> 3, hb = b & 7;
    const int t = threadIdx.x;
    for (int hh = 0; hh < 16; ++hh) {
        const int h = hb * 16 + hh;
        {
            const int ci = t & 15, w = t >> 4;
            const float v = F[(unsigned)(((d * HH + h) * WW + w) * C + ci)];
            lds[w * 17 + ci] = fmaxf(v, 0.f);
        }
        __syncthreads();
        {
            const int w = t & 15, co = t >> 4;
            out[(unsigned)(co * SP + d * HW + h * WW + w)] = lds[w * 17 + co];
        }
        __syncthreads();
    }
}

// ---------------------------------------------------------------------------
extern "C" void kernel_launch(void* const* d_in, const int* in_sizes, int n_in,
                              void* d_out, int out_size, void* d_ws, size_t ws_size,
                              hipStream_t stream)
{
    const float* x   = (const float*)d_in[0];
    const float* bng = (const float*)d_in[12];
    const float* bnb = (const float*)d_in[13];
    const float* bnm = (const float*)d_in[14];
    const float* bnv = (const float*)d_in[15];

    WSrcs ws;
    for (int i = 0; i < 11; ++i) ws.p[i] = (const float*)d_in[1 + i];

    short* XP  = (short*)d_ws;
    short* P2  = XP + PADE;
    float* F1  = (float*)(P2 + PADE);
    short* WPK = (short*)(F1 + TOT);
    float* F2  = (float*)d_out;           // fp32 scratch; fully rewritten at end

    const int pref[12] = {0, 5, 10, 60, 207, 212, 262, 409, 410, 415, 465, 612};
    int woff[11];
    for (int i = 0; i < 11; ++i) woff[i] = pref[i] * 512;   // shorts

    const dim3 blk(256);
    const dim3 pgrid(DP_ * HP_);            // 17956
    const dim3 sgrid(DD * 8);               // 1024 (small convs, final_tr)
    const dim3 tgrid(DD * 8);               // 1024 (plane convs)

    pack_all<<<dim3(612), blk, 0, stream>>>(ws, WPK);
    pack_x<<<pgrid, blk, 0, stream>>>(x, XP);

    // x1 = cbn(x, w1, 0) -> F1
    conv_mfma<3,3,1,9,false,true><<<sgrid, blk, 0, stream>>>(XP, WPK + woff[0], bng, bnb, bnm, bnv, 0, F1);
    pack_f<false,false><<<pgrid, blk, 0, stream>>>(F1, nullptr, P2);
    // F2 = x2 + x3 + x4
    conv_mfma<3,3,1,9,false,true><<<sgrid, blk, 0, stream>>>(P2, WPK + woff[1], bng, bnb, bnm, bnv, 1, F2);
    conv_plane<5,5,3,true,true><<<tgrid, blk, 0, stream>>>(P2, WPK + woff[2], bng, bnb, bnm, bnv, 2, F2);
    conv_plane<7,7,5,true,true><<<tgrid, blk, 0, stream>>>(P2, WPK + woff[3], bng, bnb, bnm, bnv, 3, F2);
    // t1p = relu(F2); F2 += F1
    pack_f<true,true><<<pgrid, blk, 0, stream>>>(F2, F1, P2);
    // F2 += x5 + x6 + x7
    conv_mfma<3,3,1,9,true,true><<<sgrid, blk, 0, stream>>>(P2, WPK + woff[4], bng, bnb, bnm, bnv, 4, F2);
    conv_plane<5,5,3,true,true><<<tgrid, blk, 0, stream>>>(P2, WPK + woff[5], bng, bnb, bnm, bnv, 5, F2);
    conv_plane<7,7,5,true,true><<<tgrid, blk, 0, stream>>>(P2, WPK + woff[6], bng, bnb, bnm, bnv, 6, F2);
    // xsp = relu(F2)
    pack_f<true,false><<<pgrid, blk, 0, stream>>>(F2, nullptr, P2);
    // F1 += y0 (1x1x1, no BN)
    conv_mfma<1,1,1,1,true,false><<<sgrid, blk, 0, stream>>>(P2, WPK + woff[7], bng, bnb, bnm, bnv, 0, F1);
    // F1 += y1, y2, y3
    conv_mfma<3,3,1,9,true,true><<<sgrid, blk, 0, stream>>>(XP, WPK + woff[8], bng, bnb, bnm, bnv, 7, F1);
    conv_plane<5,5,3,true,true><<<tgrid, blk, 0, stream>>>(XP, WPK + woff[9], bng, bnb, bnm, bnv, 8, F1);
    conv_plane<7,7,5,true,true><<<tgrid, blk, 0, stream>>>(XP, WPK + woff[10], bng, bnb, bnm, bnv, 9, F1);
    // out = relu(F1) transposed to [co][d][h][w]
    final_tr<<<sgrid, blk, 0, stream>>>(F1, (float*)d_out);

    (void)in_sizes; (void)n_in; (void)out_size; (void)ws_size;
}

// Round 10
// 169.646 us; speedup vs baseline: 1.8297x; 1.8297x over previous
//
#include <hip/hip_runtime.h>
#include <hip/hip_bf16.h>

typedef __attribute__((ext_vector_type(8))) short short8;   // 8 bf16 = 4 VGPRs
typedef __attribute__((ext_vector_type(4))) short s16x4;
typedef __attribute__((ext_vector_type(4))) float f32x4;

constexpr int C  = 16;
constexpr int DD = 128, HH = 128, WW = 16;
constexpr int HW = HH * WW;        // 2048
constexpr int SP = DD * HW;        // 262144
constexpr int TOT = C * SP;        // 4194304

// Padded bf16 activation layout: [dp=134][hp=134][wp=20][ci=16]
constexpr int WP_ = 20, HP_ = 134, DP_ = 134;
constexpr int ROWE   = WP_ * C;        // 320 elems (640 B) per row
constexpr int PLANEE = HP_ * ROWE;     // 42880
constexpr int PADE   = DP_ * PLANEE;   // 5,745,920 elems

using gas_ptr = const __attribute__((address_space(1))) void*;
using las_ptr = __attribute__((address_space(3))) void*;

// Packed-weight layout (shorts): w1 | wch | G0 | G1 | G2
constexpr int OFF_W1  = 0;            // 5 pairs
constexpr int OFF_WCH = 5 * 512;      // 1 pair
constexpr int OFF_G0  = OFF_WCH + 512;            // 147 pairs (fused 7x7x5)
constexpr int OFF_G1  = OFF_G0 + 147 * 512;
constexpr int OFF_G2  = OFF_G1 + 147 * 512;
constexpr int WPK_TOT = OFF_G2 + 147 * 512;

// ---------------------------------------------------------------------------
// Round-8 LDS-staged tiled MFMA conv, bias epilogue, optional padded-bf16
// dual write. Block 256 = 4 waves = 2 K-split pairs; pair tile 2d x 8h.
// Grid 512. PW: 0 = none, 2 = relu-write to P.
// ---------------------------------------------------------------------------
template <int KD, int KH, int KW, bool ACCUM, int PW>
__global__ __launch_bounds__(256, 2)
void conv_tile_lds(const short* __restrict__ xp, const short* __restrict__ wpk,
                   const float* __restrict__ bias, float* __restrict__ F,
                   short* __restrict__ P)
{
    constexpr int PD = (KD - 1) / 2, PH = (KH - 1) / 2, PW_ = (KW - 1) / 2;
    constexpr int KWP = (KW + 1) / 2;
    constexpr int NU  = 2 + KD - 1;
    constexpr int NUP = NU / 2;
    constexpr int NB  = 8 + KH - 1;
    constexpr int NR  = 16 + 2 * PH;
    constexpr int NCHP = NR * 40;
    constexpr int NCH  = 2 * NCHP;
    constexpr int BUFSZ = 7 * 256 * 16;
    static_assert(NCH <= 7 * 256, "stage fits in 7 iterations");

    __shared__ alignas(16) char smem[2 * BUFSZ];

    const int b    = blockIdx.x;
    const int dblk = b >> 3, hb = b & 7;
    const int d0   = dblk * 2;
    const int tid  = threadIdx.x;
    const int wid  = tid >> 6, lane = tid & 63;
    const int pid  = wid >> 1, m = wid & 1;
    const int l15  = lane & 15;
    const int cih  = (lane >> 4) & 1;
    const int tsel = lane >> 5;

    const char* xb = (const char*)xp;
    const char* wb = (const char*)wpk;
    const int hp0  = hb * 16 + (3 - PH);

    auto stage = [&](int buf, int up) {
#pragma unroll
        for (int it = 0; it < 7; ++it) {
            int chunk = it * 256 + tid;
            int cc = chunk < NCH ? chunk : NCH - 1;
            int pl = (cc >= NCHP) ? 1 : 0;
            int cp = cc - pl * NCHP;
            const char* g = xb
                + (size_t)((d0 + 2 * up + pl + (3 - PD)) * PLANEE + hp0 * ROWE) * 2
                + (size_t)cp * 16;
            void* l = (void*)(smem + buf * BUFSZ + (it * 256 + wid * 64) * 16);
            __builtin_amdgcn_global_load_lds((gas_ptr)g, (las_ptr)l, 16, 0, 0);
        }
    };

    f32x4 acc[2][8] = {};

    stage(0, 0);
#pragma unroll 1
    for (int up = 0; up < NUP; ++up) {
        const int cur = up & 1;
        if (up + 1 < NUP) {
            stage(cur ^ 1, up + 1);
            asm volatile("s_waitcnt vmcnt(7)" ::: "memory");
        } else {
            asm volatile("s_waitcnt vmcnt(0)" ::: "memory");
        }
        __builtin_amdgcn_s_barrier();

        const int u = 2 * up + m;
        const char* lb = smem + cur * BUFSZ + m * (NR * 640) + pid * 8 * 640;
#pragma unroll
        for (int kwp = 0; kwp < KWP; ++kwp) {
            const int kwa = 2 * kwp;
            const int kwb_ = (2 * kwp + 1 < KW) ? 2 * kwp + 1 : KW - 1;
            const unsigned laneoff =
                (unsigned)((l15 + (tsel ? kwb_ : kwa) + (2 - PW_)) * 32 + cih * 16);
            short8 Bf[NB];
#pragma unroll
            for (int rB = 0; rB < NB; ++rB)
                Bf[rB] = *(const short8*)(lb + rB * 640 + laneoff);
#pragma unroll
            for (int ad = 0; ad < 2; ++ad) {
                const int kd = u - ad;
                if (kd < 0 || kd >= KD) continue;
#pragma unroll
                for (int kh = 0; kh < KH; ++kh) {
                    const short8 a = *(const short8*)(
                        wb + (unsigned)(((kd * KH + kh) * KWP + kwp) * 1024 + lane * 16));
#pragma unroll
                    for (int r = 0; r < 8; ++r)
                        acc[ad][r] = __builtin_amdgcn_mfma_f32_16x16x32_bf16(
                            a, Bf[r + kh], acc[ad][r], 0, 0, 0);
                }
            }
        }
        __builtin_amdgcn_s_barrier();
    }

    // K-split merge via LDS overlay.
    float* mlds = (float*)smem;
    if (m == 1) {
#pragma unroll
        for (int ad = 0; ad < 2; ++ad)
#pragma unroll
            for (int r = 0; r < 8; ++r)
                *(f32x4*)&mlds[(((pid * 2 + ad) * 8 + r) * 64 + lane) * 4] = acc[ad][r];
    }
    __syncthreads();
    if (m == 1) return;
#pragma unroll
    for (int ad = 0; ad < 2; ++ad)
#pragma unroll
        for (int r = 0; r < 8; ++r) {
            const f32x4 o = *(const f32x4*)&mlds[(((pid * 2 + ad) * 8 + r) * 64 + lane) * 4];
#pragma unroll
            for (int j = 0; j < 4; ++j) acc[ad][r][j] += o[j];
        }

    const int cb = (lane >> 4) * 4;
    const f32x4 bv = *(const f32x4*)(bias + cb);
    const int h0 = hb * 16 + pid * 8;
#pragma unroll
    for (int ad = 0; ad < 2; ++ad)
#pragma unroll
        for (int r = 0; r < 8; ++r) {
            const int d = d0 + ad, h = h0 + r;
            float* dst = F + (unsigned)(((d * HH + h) * WW + l15) * C + cb);
            f32x4 val;
#pragma unroll
            for (int j = 0; j < 4; ++j) val[j] = acc[ad][r][j] + bv[j];
            if (PW == 2) {
                s16x4 sv;
#pragma unroll
                for (int j = 0; j < 4; ++j) {
                    __hip_bfloat16 hv = __float2bfloat16(fmaxf(val[j], 0.f));
                    sv[j] = *(short*)&hv;
                }
                *(s16x4*)(P + (size_t)(d + 3) * PLANEE + (h + 3) * ROWE
                          + (l15 + 2) * 16 + cb) = sv;
            }
            if (ACCUM) {
                const f32x4 old = *(const f32x4*)dst;
#pragma unroll
                for (int j = 0; j < 4; ++j) val[j] += old[j];
            }
            *(f32x4*)dst = val;
        }
}

// ---------------------------------------------------------------------------
// Small convs (3x3x1 with BN, 1x1x1 no BN). PW: 0 none, 1 plain bf16 write.
// ---------------------------------------------------------------------------
template <int KD, int KH, int KW, int NTAPS, bool ACCUM, bool BN, int PW>
__global__ __launch_bounds__(256, 4)
void conv_mfma(const short* __restrict__ xp, const short* __restrict__ wpk,
               const float* __restrict__ bn_g, const float* __restrict__ bn_b,
               const float* __restrict__ bn_m, const float* __restrict__ bn_v,
               int layer, float* __restrict__ F, short* __restrict__ P)
{
    constexpr int PD = (KD - 1) / 2, PH = (KH - 1) / 2, PW_ = (KW - 1) / 2;
    constexpr int NP = (NTAPS + 1) / 2;

    const int b    = blockIdx.x;
    const int d    = b >> 3, hb = b & 7;
    const int tid  = threadIdx.x;
    const int wid  = tid >> 6, lane = tid & 63;
    const int h0   = hb * 16 + wid * 4;

    const int l15  = lane & 15;
    const int cih  = (lane >> 4) & 1;
    const int tsel = lane >> 5;
    const unsigned laneoff = (unsigned)(l15 * 32 + cih * 16);

    unsigned off_r[4];
#pragma unroll
    for (int r = 0; r < 4; ++r) {
        const int h = h0 + r;
        off_r[r] = (unsigned)((((d + (3 - PD)) * HP_ + (h + (3 - PH))) * ROWE
                               + (2 - PW_) * C) * 2) + laneoff;
    }

    const char* xb = (const char*)xp;
    const char* wb = (const char*)wpk;

    f32x4 acc[4] = {};
#pragma unroll 2
    for (int p = 0; p < NP; ++p) {
        const int ta = 2 * p;
        const int tb = (2 * p + 1 < NTAPS) ? 2 * p + 1 : NTAPS - 1;
        const int kda = ta / (KH * KW), ra = ta % (KH * KW);
        const int kha = ra / KW,        kwa = ra % KW;
        const int kdb = tb / (KH * KW), rb = tb % (KH * KW);
        const int khb = rb / KW,        kwb = rb % KW;
        const unsigned toa = (unsigned)((kda * PLANEE + kha * ROWE + kwa * C) * 2);
        const unsigned tob = (unsigned)((kdb * PLANEE + khb * ROWE + kwb * C) * 2);
        const unsigned ts  = tsel ? tob : toa;

        const short8 a = *(const short8*)(wb + (unsigned)(p * 1024 + lane * 16));
#pragma unroll
        for (int r = 0; r < 4; ++r) {
            const short8 bf = *(const short8*)(xb + (off_r[r] + ts));
            acc[r] = __builtin_amdgcn_mfma_f32_16x16x32_bf16(a, bf, acc[r], 0, 0, 0);
        }
    }

    float sc[4], sh[4];
    const int cb = (lane >> 4) * 4;
    if (BN) {
        const f32x4 g  = *(const f32x4*)(bn_g + layer * C + cb);
        const f32x4 be = *(const f32x4*)(bn_b + layer * C + cb);
        const f32x4 mm = *(const f32x4*)(bn_m + layer * C + cb);
        const f32x4 v  = *(const f32x4*)(bn_v + layer * C + cb);
#pragma unroll
        for (int j = 0; j < 4; ++j) { sc[j] = g[j] / sqrtf(v[j] + 1e-5f); sh[j] = be[j] - mm[j] * sc[j]; }
    } else {
#pragma unroll
        for (int j = 0; j < 4; ++j) { sc[j] = 1.f; sh[j] = 0.f; }
    }
#pragma unroll
    for (int r = 0; r < 4; ++r) {
        const int h = h0 + r;
        float* dst = F + (unsigned)(((d * HH + h) * WW + l15) * C + cb);
        f32x4 val;
#pragma unroll
        for (int j = 0; j < 4; ++j) val[j] = acc[r][j] * sc[j] + sh[j];
        if (PW == 1) {
            s16x4 sv;
#pragma unroll
            for (int j = 0; j < 4; ++j) {
                __hip_bfloat16 hv = __float2bfloat16(val[j]);
                sv[j] = *(short*)&hv;
            }
            *(s16x4*)(P + (size_t)(d + 3) * PLANEE + (h + 3) * ROWE
                      + (l15 + 2) * 16 + cb) = sv;
        }
        if (ACCUM) {
            const f32x4 old = *(const f32x4*)dst;
#pragma unroll
            for (int j = 0; j < 4; ++j) val[j] += old[j];
        }
        *(f32x4*)dst = val;
    }
}

// ---------------------------------------------------------------------------
__global__ __launch_bounds__(256)
void pack_x(const float* __restrict__ x, short* __restrict__ xp)
{
    const int b  = blockIdx.x;
    const int dp = b / HP_, hp = b % HP_;
    const int t  = threadIdx.x;
    const int d  = dp - 3, h = hp - 3;
    const bool inr = ((unsigned)d < (unsigned)DD) && ((unsigned)h < (unsigned)HH);
    short* row = xp + (unsigned)(dp * PLANEE + hp * ROWE);

    const int w = t & 15, ci = t >> 4;
    float v = 0.f;
    if (inr) v = x[ci * SP + d * HW + h * WW + w];
    __hip_bfloat16 hv = __float2bfloat16(v);
    row[(w + 2) * C + ci] = *(short*)&hv;
    if (t < 64) {
        const int pi = t >> 4;
        const int wp = (pi < 2) ? pi : (16 + pi);
        row[wp * C + (t & 15)] = 0;
    }
}

// Zero the halo of a padded buffer (border rows + wp pads of interior rows).
__global__ __launch_bounds__(256)
void zero_halo(short* __restrict__ P)
{
    const int b  = blockIdx.x;
    const int dp = b / HP_, hp = b % HP_;
    const int t  = threadIdx.x;
    short* row = P + (unsigned)(dp * PLANEE + hp * ROWE);
    const bool border = (dp < 3) || (dp > 130) || (hp < 3) || (hp > 130);
    if (border) {
        for (int i = t; i < ROWE; i += 256) row[i] = 0;
    } else if (t < 64) {
        const int pi = t >> 4;
        const int wp = (pi < 2) ? pi : (16 + pi);
        row[wp * C + (t & 15)] = 0;
    }
}

// xsp = relu(x1_bf16 + F2), written in place over P (x1p -> xsp).
__global__ __launch_bounds__(256)
void pack_xs(short* __restrict__ P, const float* __restrict__ F2)
{
    const int b = blockIdx.x;
    const int d = b >> 7, h = b & 127;
    const int t = threadIdx.x;
    const int ci = t & 15, w = t >> 4;
    short* row = P + (size_t)(d + 3) * PLANEE + (h + 3) * ROWE;
    const int ip = (w + 2) * C + ci;
    __hip_bfloat16 hx = *(__hip_bfloat16*)&row[ip];
    float v = __bfloat162float(hx) + F2[(unsigned)(((d * HH + h) * WW + w) * C + ci)];
    __hip_bfloat16 hv = __float2bfloat16(fmaxf(v, 0.f));
    row[ip] = *(short*)&hv;
}

// ---------------------------------------------------------------------------
// pack_small: w1 (5 linear tap-pairs, BN unfolded) + wch (1 pair).
// ---------------------------------------------------------------------------
__global__ __launch_bounds__(256)
void pack_small(const float* __restrict__ w1, const float* __restrict__ wch,
                short* __restrict__ dst)
{
    const int b = blockIdx.x;
    const int t = threadIdx.x;
    const int l = t >> 2, jj = t & 3;
    const int co = l & 15, cih = (l >> 4) & 1, tp = l >> 5;
    unsigned out = 0;
    if (b < 5) {
        const int tap = 2 * b + tp;
#pragma unroll
        for (int s = 0; s < 2; ++s) {
            const int ci = cih * 8 + jj * 2 + s;
            const float v = (tap < 9) ? w1[(co * C + ci) * 9 + tap] : 0.f;
            __hip_bfloat16 hv = __float2bfloat16(v);
            out |= ((unsigned)*(unsigned short*)&hv) << (16 * s);
        }
        ((unsigned*)(dst + OFF_W1))[b * 256 + l * 4 + jj] = out;
    } else {
#pragma unroll
        for (int s = 0; s < 2; ++s) {
            const int ci = cih * 8 + jj * 2 + s;
            const float v = (tp == 0) ? wch[co * C + ci] : 0.f;
            __hip_bfloat16 hv = __float2bfloat16(v);
            out |= ((unsigned)*(unsigned short*)&hv) << (16 * s);
        }
        ((unsigned*)(dst + OFF_WCH))[l * 4 + jj] = out;
    }
}

// ---------------------------------------------------------------------------
// pack_fused: three conv-triples collapsed into 7x7x5 fused weights with BN
// scale folded in; per-group bias = sum of BN shifts. kw-paired layout.
// Groups: g0={w2,w3,w4;bn1-3}, g1={w5,w6,w7;bn4-6}, g2={wr1-3;bn7-9}.
// ---------------------------------------------------------------------------
struct W9 { const float* p[9]; };

__global__ __launch_bounds__(256)
void pack_fused(W9 w, const float* __restrict__ bng, const float* __restrict__ bnb,
                const float* __restrict__ bnm, const float* __restrict__ bnv,
                short* __restrict__ dst, float* __restrict__ bias)
{
    constexpr int kDm[3] = {3, 5, 7}, kHm[3] = {3, 5, 7}, kWm[3] = {1, 3, 5};
    constexpr int KHWm[3] = {9, 75, 245};

    const int b = blockIdx.x;
    const int g = b / 147, pr = b % 147;
    const int row = pr / 3, kwp = pr % 3;
    const int kd = row / 7, kh = row % 7;
    const int t = threadIdx.x;
    const int l = t >> 2, jj = t & 3;
    const int co = l & 15, cih = (l >> 4) & 1, tp = l >> 5;
    const int kw = 2 * kwp + tp;

    unsigned out = 0;
#pragma unroll
    for (int s = 0; s < 2; ++s) {
        const int ci = cih * 8 + jj * 2 + s;
        float val = 0.f;
        if (kw < 5) {
#pragma unroll
            for (int m = 0; m < 3; ++m) {
                const int od = (7 - kDm[m]) / 2, oh = (7 - kHm[m]) / 2, ow = (5 - kWm[m]) / 2;
                const int rd = kd - od, rh = kh - oh, rw = kw - ow;
                if ((unsigned)rd < (unsigned)kDm[m] && (unsigned)rh < (unsigned)kHm[m]
                    && (unsigned)rw < (unsigned)kWm[m]) {
                    const int layer = g * 3 + m + 1;
                    const float sbn = bng[layer * C + co] / sqrtf(bnv[layer * C + co] + 1e-5f);
                    val += sbn * w.p[g * 3 + m][(co * C + ci) * KHWm[m]
                                               + (rd * kHm[m] + rh) * kWm[m] + rw];
                }
            }
        }
        __hip_bfloat16 hv = __float2bfloat16(val);
        out |= ((unsigned)*(unsigned short*)&hv) << (16 * s);
    }
    ((unsigned*)(dst + OFF_G0))[(g * 147 + pr) * 256 + l * 4 + jj] = out;

    if (pr == 0 && t < 16) {
        float bsum = 0.f;
#pragma unroll
        for (int m = 0; m < 3; ++m) {
            const int layer = g * 3 + m + 1;
            const float sbn = bng[layer * C + t] / sqrtf(bnv[layer * C + t] + 1e-5f);
            bsum += bnb[layer * C + t] - bnm[layer * C + t] * sbn;
        }
        bias[g * 16 + t] = bsum;
    }
}

// ---------------------------------------------------------------------------
__global__ __launch_bounds__(256)
void final_tr(const float* __restrict__ F, float* __restrict__ out)
{
    __shared__ float lds[16 * 17];
    const int b = blockIdx.x;
    const int d = b >> 3, hb = b & 7;
    const int t = threadIdx.x;
    for (int hh = 0; hh < 16; ++hh) {
        const int h = hb * 16 + hh;
        {
            const int ci = t & 15, w = t >> 4;
            const float v = F[(unsigned)(((d * HH + h) * WW + w) * C + ci)];
            lds[w * 17 + ci] = fmaxf(v, 0.f);
        }
        __syncthreads();
        {
            const int w = t & 15, co = t >> 4;
            out[(unsigned)(co * SP + d * HW + h * WW + w)] = lds[w * 17 + co];
        }
        __syncthreads();
    }
}

// ---------------------------------------------------------------------------
extern "C" void kernel_launch(void* const* d_in, const int* in_sizes, int n_in,
                              void* d_out, int out_size, void* d_ws, size_t ws_size,
                              hipStream_t stream)
{
    const float* x   = (const float*)d_in[0];
    const float* w1  = (const float*)d_in[1];
    const float* wch = (const float*)d_in[8];
    const float* bng = (const float*)d_in[12];
    const float* bnb = (const float*)d_in[13];
    const float* bnm = (const float*)d_in[14];
    const float* bnv = (const float*)d_in[15];

    W9 w9;
    w9.p[0] = (const float*)d_in[2];  w9.p[1] = (const float*)d_in[3];
    w9.p[2] = (const float*)d_in[4];  w9.p[3] = (const float*)d_in[5];
    w9.p[4] = (const float*)d_in[6];  w9.p[5] = (const float*)d_in[7];
    w9.p[6] = (const float*)d_in[9];  w9.p[7] = (const float*)d_in[10];
    w9.p[8] = (const float*)d_in[11];

    short* XP   = (short*)d_ws;            // x packed -> later t1p
    short* PA   = XP + PADE;               // x1p -> xsp
    float* F1   = (float*)(PA + PADE);     // x1 (+ y0..y3)
    short* WPK  = (short*)(F1 + TOT);
    float* BIAS = (float*)(WPK + WPK_TOT); // 48 floats
    float* F2   = (float*)d_out;           // x2+..+x7 scratch; overwritten at end

    const dim3 blk(256);
    const dim3 pgrid(DP_ * HP_);           // 17956
    const dim3 sgrid(DD * 8);              // 1024 (small convs, final_tr)
    const dim3 tgrid((DD / 2) * 8);        // 512  (tile convs)

    zero_halo<<<pgrid, blk, 0, stream>>>(PA);
    pack_x<<<pgrid, blk, 0, stream>>>(x, XP);
    pack_small<<<dim3(6), blk, 0, stream>>>(w1, wch, WPK);
    pack_fused<<<dim3(441), blk, 0, stream>>>(w9, bng, bnb, bnm, bnv, WPK, BIAS);

    // F1 = x1 = cbn(x, w1, 0); PA = x1p (bf16, no relu)
    conv_mfma<3,3,1,9,false,true,1><<<sgrid, blk, 0, stream>>>(
        XP, WPK + OFF_W1, bng, bnb, bnm, bnv, 0, F1, PA);
    // F1 += y1+y2+y3 (fused G2 over x; XP still holds x)
    conv_tile_lds<7,7,5,true,0><<<tgrid, blk, 0, stream>>>(
        XP, WPK + OFF_G2, BIAS + 32, F1, nullptr);
    // F2 = x2+x3+x4 (fused G0 over x1p); XP <- t1p = relu(F2)
    conv_tile_lds<7,7,5,false,2><<<tgrid, blk, 0, stream>>>(
        PA, WPK + OFF_G0, BIAS + 0, F2, XP);
    // F2 += x5+x6+x7 (fused G1 over t1p)
    conv_tile_lds<7,7,5,true,0><<<tgrid, blk, 0, stream>>>(
        XP, WPK + OFF_G1, BIAS + 16, F2, nullptr);
    // PA <- xsp = relu(x1_bf16 + F2)
    pack_xs<<<dim3(DD * HH), blk, 0, stream>>>(PA, F2);
    // F1 += y0 = conv1x1(xs) (no BN)
    conv_mfma<1,1,1,1,true,false,0><<<sgrid, blk, 0, stream>>>(
        PA, WPK + OFF_WCH, nullptr, nullptr, nullptr, nullptr, 0, F1, nullptr);
    // out = relu(F1) transposed to [co][d][h][w]
    final_tr<<<sgrid, blk, 0, stream>>>(F1, (float*)d_out);

    (void)in_sizes; (void)n_in; (void)out_size; (void)ws_size;
}